// Round 13
// baseline (147.711 us; speedup 1.0000x reference)
//
#include <hip/hip_runtime.h>
#include <hip/hip_fp16.h>
#include <cstdint>

#define BB 2
#define SS 512
#define EE 256
#define NN (BB*SS)           // 1024 rows
#define KTOT (EE*EE)         // 65536
#define SPLITK 32
#define KCHUNK (KTOT/SPLITK) // 2048
#define NSTEP (KCHUNK/32)    // 64 k-steps per chunk
#define TSTEPS (KTOT/32)     // 2048 total k-steps
#define LN_EPS 1e-3f

typedef _Float16 f16;
typedef _Float16 f16x8 __attribute__((ext_vector_type(8)));
typedef float    f32x4 __attribute__((ext_vector_type(4)));

// ---------------- Kernel 1a: tiled triangular weighted prefix partials.
__global__ void wprefix_kernel(const float* __restrict__ x, float* __restrict__ ps) {
    __shared__ float xt[64][128];
    __shared__ float wl2[576];
    const int id = blockIdx.x;             // 144 blocks
    const int eh = id & 1;
    const int rest = id >> 1;
    const int b = rest / 36;
    const int r = rest % 36;
    int it = 0;
    while ((it + 1) * (it + 2) / 2 <= r) ++it;
    const int jt = r - it * (it + 1) / 2;
    const int tid = threadIdx.x;

    for (int t = tid; t < 576; t += 256) {
        const int d = t - 64;
        wl2[t] = (d > 0) ? 1.0f / ((float)d * (float)d) : 0.0f;
    }
    const int jbase = jt * 64, ibase = it * 64;
    const float* xb = x + ((size_t)b * SS + jbase) * EE + eh * 128;
    #pragma unroll
    for (int p = 0; p < 8; ++p) {
        const int row = p * 8 + (tid >> 5);
        const int col = (tid & 31) * 4;
        *(float4*)&xt[row][col] = *(const float4*)(xb + (size_t)row * EE + col);
    }
    __syncthreads();

    const int g  = tid >> 5;
    const int ec = (tid & 31) * 4;
    const int irow = ibase + g * 8;
    float4 acc[8];
    #pragma unroll
    for (int m = 0; m < 8; ++m) acc[m] = (float4){0.f, 0.f, 0.f, 0.f};

    for (int jj = 0; jj < 64; ++jj) {
        const float4 xv = *(const float4*)&xt[jj][ec];
        const int wbase = irow - (jbase + jj) + 64;
        #pragma unroll
        for (int m = 0; m < 8; ++m) {
            const float w = wl2[wbase + m];
            acc[m].x += xv.x * w;
            acc[m].y += xv.y * w;
            acc[m].z += xv.z * w;
            acc[m].w += xv.w * w;
        }
    }

    float* base = ps + ((size_t)(((b * 2 + eh) * 8 + it) * 8 + jt)) * (64 * 128);
    #pragma unroll
    for (int m = 0; m < 8; ++m)
        *(float4*)(base + (size_t)(g * 8 + m) * 128 + ec) = acc[m];
}

// ---------------- Kernel 1b: fold j-tile partials -> s[n,e]
__global__ void reduce_s_kernel(const float* __restrict__ ps, float* __restrict__ s) {
    const int n = blockIdx.x;
    const int e = threadIdx.x;
    const int b = n >> 9, i = n & (SS - 1);
    const int it = i >> 6, il = i & 63;
    const int eh = e >> 7, ec = e & 127;
    const size_t tbase = (size_t)((b * 2 + eh) * 8 + it) * 8;
    float acc = 0.0f;
    for (int jt = 0; jt <= it; ++jt)
        acc += ps[(tbase + jt) * (64 * 128) + (size_t)il * 128 + ec];
    s[(size_t)n * EE + e] = acc;
}

// ---------------- Kernel 2: pack/transpose cm f32 -> cmP f16 in GEMM staging order.
// Block t covers k in [t*32,+32). Layout: idx = koct*2048 + c*8 + j
//   <-> cm[c][t*32 + koct*8 + j]
__global__ void pack_kernel(const float* __restrict__ cm, f16* __restrict__ cmP) {
    const int t    = blockIdx.x;
    const int tid  = threadIdx.x;
    const int slot = tid >> 6;
    const int cq   = (tid & 63) * 4;
    const float* src = cm + (size_t)t * 32 + slot * 8;
    f16* dst = cmP + (size_t)t * 8192 + tid * 32;
    #pragma unroll
    for (int u = 0; u < 4; ++u) {
        const float* row = src + (size_t)(cq + u) * KTOT;
        float4 lo = *(const float4*)(row);
        float4 hi = *(const float4*)(row + 4);
        f16x8 h = { (f16)lo.x, (f16)lo.y, (f16)lo.z, (f16)lo.w,
                    (f16)hi.x, (f16)hi.y, (f16)hi.z, (f16)hi.w };
        *(f16x8*)(dst + u * 8) = h;
    }
}

// ---------------- Kernel 3: split-K MFMA GEMM — 1-wave blocks (64 thr),
// 12 KB LDS (3 bufs x 4 KB) => ~13 waves/CU (was 8). Per-wave pipeline
// identical to R11: barrier-free, stage==read-set, depth-2 counted vmcnt,
// tail bf/af prefetch. Grid 2048 = 16 nblocks x 32 chunks x 4 col-quarters.
__launch_bounds__(64, 4)
__global__ void gemm_kernel(const float* __restrict__ x,
                            const float* __restrict__ sbuf,
                            const f16* __restrict__ cmP,
                            float* __restrict__ part) {
    __shared__ __align__(16) f16 Bs[3][2048];   // 3 x 4 KB (per-wave slice)
    const int lane = threadIdx.x;
    const int koct = lane >> 4;      // k-octet 0..3
    const int cl   = lane & 15;

    const int d   = blockIdx.x;          // 0..2047
    const int xcd = d & 7;
    const int e   = d >> 3;              // 0..255
    const int chunk  = xcd * 4 + (e >> 6);   // 0..31, 4 chunks per XCD
    const int rem    = e & 63;
    const int nblock = rem >> 2;             // 0..15
    const int wq     = rem & 3;              // col-quarter 0..3

    // ---- xf loads (8 global loads)
    f16x8 xf[4];
    #pragma unroll
    for (int rt = 0; rt < 4; ++rt) {
        const int r = nblock * 64 + rt * 16 + cl;
        const float* xr = x + (size_t)r * EE + chunk * 8;
        float4 xlo = *(const float4*)(xr);
        float4 xhi = *(const float4*)(xr + 4);
        xf[rt] = (f16x8){ (f16)xlo.x, (f16)xlo.y, (f16)xlo.z, (f16)xlo.w,
                          (f16)xhi.x, (f16)xhi.y, (f16)xhi.z, (f16)xhi.w };
    }
    // ---- svm m=0 loads (8 global loads)
    float4 p0[4][2];
    #pragma unroll
    for (int rt = 0; rt < 4; ++rt) {
        const int r = nblock * 64 + rt * 16 + cl;
        const float* sr = sbuf + (size_t)r * EE + koct * 8;
        p0[rt][0] = *(const float4*)(sr);
        p0[rt][1] = *(const float4*)(sr + 4);
    }
    __builtin_amdgcn_sched_barrier(0);   // pin: xf/svm issued before stages

    f32x4 acc[4][4];
    #pragma unroll
    for (int a = 0; a < 4; ++a)
        #pragma unroll
        for (int b = 0; b < 4; ++b) acc[a][b] = (f32x4){0.f, 0.f, 0.f, 0.f};

    const char* srcBase = (const char*)cmP + (size_t)(chunk * NSTEP) * 16384;
    // step v -> B block t = ((v&7)<<3)|(v>>3). This wave stages its own
    // read-set: global {t*16384 + i*4096 + wq*1024 + lane*16} ->
    // LDS {buf(v%3) + i*1024 + lane*16}, i=0..3.
    auto stageV = [&](int v) {
        const int t = ((v & 7) << 3) | (v >> 3);
        const char* g = srcBase + (size_t)t * 16384 + wq * 1024 + lane * 16;
        char* l = (char*)&Bs[v % 3][0] + lane * 16;
        #pragma unroll
        for (int i = 0; i < 4; ++i) {
            __builtin_amdgcn_global_load_lds(
                (const __attribute__((address_space(1))) void*)(g + i * 4096),
                (__attribute__((address_space(3))) void*)(l + i * 1024),
                16, 0, 0);
        }
    };

    stageV(0); stageV(1);                // depth-2
    asm volatile("s_waitcnt vmcnt(4)" ::: "memory");   // xf, svm, stage(0) done
    __builtin_amdgcn_sched_barrier(0);

    f16x8 svm[4];
    #pragma unroll
    for (int rt = 0; rt < 4; ++rt)
        svm[rt] = (f16x8){ (f16)p0[rt][0].x, (f16)p0[rt][0].y,
                           (f16)p0[rt][0].z, (f16)p0[rt][0].w,
                           (f16)p0[rt][1].x, (f16)p0[rt][1].y,
                           (f16)p0[rt][1].z, (f16)p0[rt][1].w };

    const int cb = koct * 512 + cl * 8;   // f16 idx within 2048-f16 buf

    f16x8 bfc[4], afc[4];
    {
        const f16* bb = &Bs[0][cb];
        #pragma unroll
        for (int ct = 0; ct < 4; ++ct) bfc[ct] = *(const f16x8*)(bb + ct * 128);
        #pragma unroll
        for (int rt = 0; rt < 4; ++rt) {
            const f16 xa = xf[rt][0];
            #pragma unroll
            for (int j = 0; j < 8; ++j) afc[rt][j] = xa * svm[rt][j];
        }
    }

    #pragma unroll
    for (int m = 0; m < 8; ++m) {
        float4 pnxt[4][2];
        #pragma unroll
        for (int a_l = 0; a_l < 8; ++a_l) {
            const int v = m * 8 + a_l;

            // issue next-m svm loads early (order-pinned before MFMA/stage)
            if (a_l == 6 && m < 7) {
                #pragma unroll
                for (int rt = 0; rt < 4; ++rt) {
                    const int r = nblock * 64 + rt * 16 + cl;
                    const float* sr = sbuf + (size_t)r * EE + (m + 1) * 32 + koct * 8;
                    pnxt[rt][0] = *(const float4*)(sr);
                    pnxt[rt][1] = *(const float4*)(sr + 4);
                }
                __builtin_amdgcn_sched_barrier(0);
            }

            // MFMA cluster (16) — operands prefetched last step
            __builtin_amdgcn_s_setprio(1);
            #pragma unroll
            for (int ct = 0; ct < 4; ++ct)
                #pragma unroll
                for (int rt = 0; rt < 4; ++rt)
                    acc[rt][ct] = __builtin_amdgcn_mfma_f32_16x16x32_f16(afc[rt], bfc[ct], acc[rt][ct], 0, 0, 0);
            __builtin_amdgcn_s_setprio(0);

            if (v + 2 < NSTEP) stageV(v + 2);

            // counted waits (depth-2): guarantee stage(v+1) (and svm) arrived
            if (v <= 61) {
                if (a_l == 6 && m < 7)      asm volatile("s_waitcnt vmcnt(12)" ::: "memory");
                else                        asm volatile("s_waitcnt vmcnt(4)"  ::: "memory");
            } else if (v == 62)             asm volatile("s_waitcnt vmcnt(0)"  ::: "memory");
            __builtin_amdgcn_sched_barrier(0);

            // tail prefetch: bf(v+1) + af(v+1)
            if (v < 63) {
                const f16* bb = &Bs[0][0] + (size_t)((v + 1) % 3) * 2048 + cb;
                f16x8 bfn[4];
                #pragma unroll
                for (int ct = 0; ct < 4; ++ct) bfn[ct] = *(const f16x8*)(bb + ct * 128);
                if (a_l == 7) {   // new m's svm (loads guaranteed done)
                    #pragma unroll
                    for (int rt = 0; rt < 4; ++rt)
                        svm[rt] = (f16x8){ (f16)pnxt[rt][0].x, (f16)pnxt[rt][0].y,
                                           (f16)pnxt[rt][0].z, (f16)pnxt[rt][0].w,
                                           (f16)pnxt[rt][1].x, (f16)pnxt[rt][1].y,
                                           (f16)pnxt[rt][1].z, (f16)pnxt[rt][1].w };
                }
                f16x8 afn[4];
                #pragma unroll
                for (int rt = 0; rt < 4; ++rt) {
                    const f16 xa = xf[rt][(a_l + 1) & 7];
                    #pragma unroll
                    for (int j = 0; j < 8; ++j) afn[rt][j] = xa * svm[rt][j];
                }
                #pragma unroll
                for (int ct = 0; ct < 4; ++ct) bfc[ct] = bfn[ct];
                #pragma unroll
                for (int rt = 0; rt < 4; ++rt) afc[rt] = afn[rt];
                __builtin_amdgcn_sched_barrier(0);   // keep prefetch in step v
            }
        }
    }

    // Epilogue: C/D layout col = lane&15, row = (lane>>4)*4 + reg ; f32 stores
    #pragma unroll
    for (int rt = 0; rt < 4; ++rt) {
        #pragma unroll
        for (int ct = 0; ct < 4; ++ct) {
            const int c  = wq * 64 + ct * 16 + cl;
            const int rb = nblock * 64 + rt * 16 + koct * 4;
            #pragma unroll
            for (int q = 0; q < 4; ++q)
                part[((size_t)chunk * NN + rb + q) * EE + c] = acc[rt][ct][q];
        }
    }
}

// ---------------- Kernel 4: split-K reduce + residual + LayerNorm
__global__ void reduce_ln_kernel(const float* __restrict__ x,
                                 const float* __restrict__ part,
                                 const float* __restrict__ gamma,
                                 const float* __restrict__ beta,
                                 float* __restrict__ out) {
    const int n = blockIdx.x;
    const int c = threadIdx.x;
    const int lane = c & 63, wave = c >> 6;
    float y = x[(size_t)n * EE + c];
    #pragma unroll 8
    for (int ch = 0; ch < SPLITK; ++ch)
        y += part[((size_t)ch * NN + n) * EE + c];

    float v = y;
    #pragma unroll
    for (int o = 32; o > 0; o >>= 1) v += __shfl_xor(v, o);
    __shared__ float red[8];
    if (lane == 0) red[wave] = v;
    __syncthreads();
    const float mean = (red[0] + red[1] + red[2] + red[3]) * (1.0f / EE);
    const float d = y - mean;
    float sq = d * d;
    #pragma unroll
    for (int o = 32; o > 0; o >>= 1) sq += __shfl_xor(sq, o);
    if (lane == 0) red[4 + wave] = sq;
    __syncthreads();
    const float var = (red[4] + red[5] + red[6] + red[7]) * (1.0f / EE);
    out[(size_t)n * EE + c] = d * rsqrtf(var + LN_EPS) * gamma[c] + beta[c];
}

extern "C" void kernel_launch(void* const* d_in, const int* in_sizes, int n_in,
                              void* d_out, int out_size, void* d_ws, size_t ws_size,
                              hipStream_t stream) {
    const float* x     = (const float*)d_in[0];
    const float* cm    = (const float*)d_in[1];
    const float* gamma = (const float*)d_in[2];
    const float* beta  = (const float*)d_in[3];
    float* out = (float*)d_out;

    float* sbuf = (float*)d_ws;                                    // 1 MB
    f16*   cmP  = (f16*)(sbuf + (size_t)NN * EE);                  // 33.5 MB
    float* part = (float*)((char*)cmP + (size_t)TSTEPS * 8192 * sizeof(f16)); // 33.5 MB
    float* ps   = part;   // prefix partials (8.4 MB) alias part — consumed
                          // by reduce_s before gemm writes part.

    hipLaunchKernelGGL(wprefix_kernel, dim3(144), dim3(256), 0, stream, x, ps);
    hipLaunchKernelGGL(reduce_s_kernel, dim3(NN), dim3(256), 0, stream, ps, sbuf);
    hipLaunchKernelGGL(pack_kernel, dim3(TSTEPS), dim3(256), 0, stream, cm, cmP);
    hipLaunchKernelGGL(gemm_kernel, dim3(16 * SPLITK * 4), dim3(64), 0, stream,
                       x, sbuf, cmP, part);
    hipLaunchKernelGGL(reduce_ln_kernel, dim3(NN), dim3(256), 0, stream,
                       x, part, gamma, beta, out);
}

// Round 14
// 81.902 us; speedup vs baseline: 1.8035x; 1.8035x over previous
//
#include <hip/hip_runtime.h>
#include <hip/hip_fp16.h>
#include <cstdint>

#define BB 2
#define SS 512
#define EE 256
#define NN (BB*SS)           // 1024 rows
#define KTOT (EE*EE)         // 65536
#define SPLITK 32
#define KCHUNK (KTOT/SPLITK) // 2048
#define NSTEP (KCHUNK/32)    // 64 k-steps per chunk
#define TSTEPS (KTOT/32)     // 2048 total k-steps
#define LN_EPS 1e-3f

typedef _Float16 f16;
typedef _Float16 f16x8 __attribute__((ext_vector_type(8)));
typedef float    f32x4 __attribute__((ext_vector_type(4)));

// ---------------- Kernel 1: FUSED pack + wprefix (independent work).
// Blocks [0, TSTEPS): pack cm f32 -> cmP f16 (staging order).
// Blocks [TSTEPS, TSTEPS+144): triangular weighted prefix partials.
__global__ void prep_kernel(const float* __restrict__ cm, f16* __restrict__ cmP,
                            const float* __restrict__ x, float* __restrict__ ps) {
    __shared__ float xt[64][128];
    __shared__ float wl2[576];
    const int bid = blockIdx.x;
    const int tid = threadIdx.x;

    if (bid < TSTEPS) {
        // ---- pack: block t covers k in [t*32,+32). idx = slot*2048 + c*8 + j
        const int t    = bid;
        const int slot = tid >> 6;
        const int cq   = (tid & 63) * 4;
        const float* src = cm + (size_t)t * 32 + slot * 8;
        f16* dst = cmP + (size_t)t * 8192 + tid * 32;
        #pragma unroll
        for (int u = 0; u < 4; ++u) {
            const float* row = src + (size_t)(cq + u) * KTOT;
            float4 lo = *(const float4*)(row);
            float4 hi = *(const float4*)(row + 4);
            f16x8 h = { (f16)lo.x, (f16)lo.y, (f16)lo.z, (f16)lo.w,
                        (f16)hi.x, (f16)hi.y, (f16)hi.z, (f16)hi.w };
            *(f16x8*)(dst + u * 8) = h;
        }
        return;
    }

    // ---- wprefix
    const int id = bid - TSTEPS;           // 0..143
    const int eh = id & 1;
    const int rest = id >> 1;
    const int b = rest / 36;
    const int r = rest % 36;
    int it = 0;
    while ((it + 1) * (it + 2) / 2 <= r) ++it;
    const int jt = r - it * (it + 1) / 2;

    for (int t = tid; t < 576; t += 256) {
        const int d = t - 64;
        wl2[t] = (d > 0) ? 1.0f / ((float)d * (float)d) : 0.0f;
    }
    const int jbase = jt * 64, ibase = it * 64;
    const float* xb = x + ((size_t)b * SS + jbase) * EE + eh * 128;
    #pragma unroll
    for (int p = 0; p < 8; ++p) {
        const int row = p * 8 + (tid >> 5);
        const int col = (tid & 31) * 4;
        *(float4*)&xt[row][col] = *(const float4*)(xb + (size_t)row * EE + col);
    }
    __syncthreads();

    const int g  = tid >> 5;
    const int ec = (tid & 31) * 4;
    const int irow = ibase + g * 8;
    float4 acc[8];
    #pragma unroll
    for (int m = 0; m < 8; ++m) acc[m] = (float4){0.f, 0.f, 0.f, 0.f};

    for (int jj = 0; jj < 64; ++jj) {
        const float4 xv = *(const float4*)&xt[jj][ec];
        const int wbase = irow - (jbase + jj) + 64;
        #pragma unroll
        for (int m = 0; m < 8; ++m) {
            const float w = wl2[wbase + m];
            acc[m].x += xv.x * w;
            acc[m].y += xv.y * w;
            acc[m].z += xv.z * w;
            acc[m].w += xv.w * w;
        }
    }

    float* base = ps + ((size_t)(((b * 2 + eh) * 8 + it) * 8 + jt)) * (64 * 128);
    #pragma unroll
    for (int m = 0; m < 8; ++m)
        *(float4*)(base + (size_t)(g * 8 + m) * 128 + ec) = acc[m];
}

// ---------------- Kernel 1b: fold j-tile partials -> s[n,e]
__global__ void reduce_s_kernel(const float* __restrict__ ps, float* __restrict__ s) {
    const int n = blockIdx.x;
    const int e = threadIdx.x;
    const int b = n >> 9, i = n & (SS - 1);
    const int it = i >> 6, il = i & 63;
    const int eh = e >> 7, ec = e & 127;
    const size_t tbase = (size_t)((b * 2 + eh) * 8 + it) * 8;
    float acc = 0.0f;
    for (int jt = 0; jt <= it; ++jt)
        acc += ps[(tbase + jt) * (64 * 128) + (size_t)il * 128 + ec];
    s[(size_t)n * EE + e] = acc;
}

// ---------------- Kernel 2: split-K MFMA GEMM — R11 structure (barrier-free,
// depth-3, tail bf/af prefetch) + pk-mul af build (f16x8 splat * vector).
__launch_bounds__(256, 2)
__global__ void gemm_kernel(const float* __restrict__ x,
                            const float* __restrict__ sbuf,
                            const f16* __restrict__ cmP,
                            float* __restrict__ part) {
    __shared__ __align__(16) f16 Bs[4][8192];   // 4 x 16 KB
    const int tid  = threadIdx.x;
    const int lane = tid & 63;
    const int wave = tid >> 6;       // col-quarter 0..3
    const int koct = lane >> 4;      // k-octet 0..3
    const int cl   = lane & 15;

    const int d = blockIdx.x;            // 0..511
    const int nblock = (d >> 3) & 15;
    const int chunk  = (d & 7) * 4 + (d >> 7);   // XCD-grouped chunks

    // ---- xf loads (8 global loads)
    f16x8 xf[4];
    #pragma unroll
    for (int rt = 0; rt < 4; ++rt) {
        const int r = nblock * 64 + rt * 16 + cl;
        const float* xr = x + (size_t)r * EE + chunk * 8;
        float4 xlo = *(const float4*)(xr);
        float4 xhi = *(const float4*)(xr + 4);
        xf[rt] = (f16x8){ (f16)xlo.x, (f16)xlo.y, (f16)xlo.z, (f16)xlo.w,
                          (f16)xhi.x, (f16)xhi.y, (f16)xhi.z, (f16)xhi.w };
    }
    // ---- svm m=0 loads (8 global loads)
    float4 p0[4][2];
    #pragma unroll
    for (int rt = 0; rt < 4; ++rt) {
        const int r = nblock * 64 + rt * 16 + cl;
        const float* sr = sbuf + (size_t)r * EE + koct * 8;
        p0[rt][0] = *(const float4*)(sr);
        p0[rt][1] = *(const float4*)(sr + 4);
    }
    __builtin_amdgcn_sched_barrier(0);   // pin: xf/svm issued before stages

    f32x4 acc[4][4];
    #pragma unroll
    for (int a = 0; a < 4; ++a)
        #pragma unroll
        for (int b = 0; b < 4; ++b) acc[a][b] = (f32x4){0.f, 0.f, 0.f, 0.f};

    const char* srcBase = (const char*)cmP + (size_t)(chunk * NSTEP) * 16384;
    auto stageV = [&](int v) {
        const int t = ((v & 7) << 3) | (v >> 3);
        const char* g = srcBase + (size_t)t * 16384 + wave * 1024 + lane * 16;
        char* l = (char*)&Bs[v & 3][0] + wave * 1024;
        #pragma unroll
        for (int i = 0; i < 4; ++i) {
            __builtin_amdgcn_global_load_lds(
                (const __attribute__((address_space(1))) void*)(g + i * 4096),
                (__attribute__((address_space(3))) void*)(l + i * 4096),
                16, 0, 0);
        }
    };

    stageV(0); stageV(1); stageV(2);     // 12 loads in flight (per wave)
    asm volatile("s_waitcnt vmcnt(8)" ::: "memory");   // xf, svm, stage(0) done
    __builtin_amdgcn_sched_barrier(0);

    f16x8 svm[4];
    #pragma unroll
    for (int rt = 0; rt < 4; ++rt)
        svm[rt] = (f16x8){ (f16)p0[rt][0].x, (f16)p0[rt][0].y,
                           (f16)p0[rt][0].z, (f16)p0[rt][0].w,
                           (f16)p0[rt][1].x, (f16)p0[rt][1].y,
                           (f16)p0[rt][1].z, (f16)p0[rt][1].w };

    const int cb = koct * 2048 + (wave * 64 + cl) * 8;

    // bf(0) read + af(0) build
    f16x8 bfc[4], afc[4];
    {
        const f16* bb = &Bs[0][cb];
        #pragma unroll
        for (int ct = 0; ct < 4; ++ct) bfc[ct] = *(const f16x8*)(bb + ct * 128);
        #pragma unroll
        for (int rt = 0; rt < 4; ++rt) {
            const f16 xa = xf[rt][0];
            const f16x8 xa8 = { xa, xa, xa, xa, xa, xa, xa, xa };
            afc[rt] = xa8 * svm[rt];          // 4 x v_pk_mul_f16
        }
    }

    #pragma unroll
    for (int m = 0; m < 8; ++m) {
        float4 pnxt[4][2];
        #pragma unroll
        for (int a_l = 0; a_l < 8; ++a_l) {
            const int v = m * 8 + a_l;

            // issue next-m svm loads early (order-pinned before MFMA/stage)
            if (a_l == 6 && m < 7) {
                #pragma unroll
                for (int rt = 0; rt < 4; ++rt) {
                    const int r = nblock * 64 + rt * 16 + cl;
                    const float* sr = sbuf + (size_t)r * EE + (m + 1) * 32 + koct * 8;
                    pnxt[rt][0] = *(const float4*)(sr);
                    pnxt[rt][1] = *(const float4*)(sr + 4);
                }
                __builtin_amdgcn_sched_barrier(0);
            }

            // MFMA cluster (16) — operands prefetched last step
            __builtin_amdgcn_s_setprio(1);
            #pragma unroll
            for (int ct = 0; ct < 4; ++ct)
                #pragma unroll
                for (int rt = 0; rt < 4; ++rt)
                    acc[rt][ct] = __builtin_amdgcn_mfma_f32_16x16x32_f16(afc[rt], bfc[ct], acc[rt][ct], 0, 0, 0);
            __builtin_amdgcn_s_setprio(0);

            if (v + 3 < NSTEP) stageV(v + 3);

            // counted waits: guarantee stage(v+1) (and svm at a_l==7) arrived
            if (v <= 60) {
                if (a_l == 6 && m < 7) asm volatile("s_waitcnt vmcnt(16)" ::: "memory");
                else                   asm volatile("s_waitcnt vmcnt(8)"  ::: "memory");
            } else if (v == 61)        asm volatile("s_waitcnt vmcnt(4)"  ::: "memory");
            else if (v == 62)          asm volatile("s_waitcnt vmcnt(0)"  ::: "memory");
            __builtin_amdgcn_sched_barrier(0);

            // tail prefetch: bf(v+1) + af(v+1)
            if (v < 63) {
                const f16* bb = &Bs[0][0] + (size_t)((v + 1) & 3) * 8192 + cb;
                f16x8 bfn[4];
                #pragma unroll
                for (int ct = 0; ct < 4; ++ct) bfn[ct] = *(const f16x8*)(bb + ct * 128);
                if (a_l == 7) {   // new m's svm (loads guaranteed done)
                    #pragma unroll
                    for (int rt = 0; rt < 4; ++rt)
                        svm[rt] = (f16x8){ (f16)pnxt[rt][0].x, (f16)pnxt[rt][0].y,
                                           (f16)pnxt[rt][0].z, (f16)pnxt[rt][0].w,
                                           (f16)pnxt[rt][1].x, (f16)pnxt[rt][1].y,
                                           (f16)pnxt[rt][1].z, (f16)pnxt[rt][1].w };
                }
                #pragma unroll
                for (int rt = 0; rt < 4; ++rt) {
                    const f16 xa = xf[rt][(a_l + 1) & 7];
                    const f16x8 xa8 = { xa, xa, xa, xa, xa, xa, xa, xa };
                    const f16x8 afn = xa8 * svm[rt];   // 4 x v_pk_mul_f16
                    afc[rt] = afn;
                }
                #pragma unroll
                for (int ct = 0; ct < 4; ++ct) bfc[ct] = bfn[ct];
                __builtin_amdgcn_sched_barrier(0);   // keep prefetch in step v
            }
        }
    }

    // Epilogue: C/D layout col = lane&15, row = (lane>>4)*4 + reg ; f32 stores
    #pragma unroll
    for (int rt = 0; rt < 4; ++rt) {
        #pragma unroll
        for (int ct = 0; ct < 4; ++ct) {
            const int c  = wave * 64 + ct * 16 + cl;
            const int rb = nblock * 64 + rt * 16 + koct * 4;
            #pragma unroll
            for (int q = 0; q < 4; ++q)
                part[((size_t)chunk * NN + rb + q) * EE + c] = acc[rt][ct][q];
        }
    }
}

// ---------------- Kernel 3: split-K reduce + residual + LayerNorm
__global__ void reduce_ln_kernel(const float* __restrict__ x,
                                 const float* __restrict__ part,
                                 const float* __restrict__ gamma,
                                 const float* __restrict__ beta,
                                 float* __restrict__ out) {
    const int n = blockIdx.x;
    const int c = threadIdx.x;
    const int lane = c & 63, wave = c >> 6;
    float y = x[(size_t)n * EE + c];
    #pragma unroll 8
    for (int ch = 0; ch < SPLITK; ++ch)
        y += part[((size_t)ch * NN + n) * EE + c];

    float v = y;
    #pragma unroll
    for (int o = 32; o > 0; o >>= 1) v += __shfl_xor(v, o);
    __shared__ float red[8];
    if (lane == 0) red[wave] = v;
    __syncthreads();
    const float mean = (red[0] + red[1] + red[2] + red[3]) * (1.0f / EE);
    const float d = y - mean;
    float sq = d * d;
    #pragma unroll
    for (int o = 32; o > 0; o >>= 1) sq += __shfl_xor(sq, o);
    if (lane == 0) red[4 + wave] = sq;
    __syncthreads();
    const float var = (red[4] + red[5] + red[6] + red[7]) * (1.0f / EE);
    out[(size_t)n * EE + c] = d * rsqrtf(var + LN_EPS) * gamma[c] + beta[c];
}

extern "C" void kernel_launch(void* const* d_in, const int* in_sizes, int n_in,
                              void* d_out, int out_size, void* d_ws, size_t ws_size,
                              hipStream_t stream) {
    const float* x     = (const float*)d_in[0];
    const float* cm    = (const float*)d_in[1];
    const float* gamma = (const float*)d_in[2];
    const float* beta  = (const float*)d_in[3];
    float* out = (float*)d_out;

    float* sbuf = (float*)d_ws;                                    // 1 MB
    f16*   cmP  = (f16*)(sbuf + (size_t)NN * EE);                  // 33.5 MB
    float* part = (float*)((char*)cmP + (size_t)TSTEPS * 8192 * sizeof(f16)); // 33.5 MB
    float* ps   = part;   // prefix partials (8.4 MB) alias part — consumed
                          // by reduce_s before gemm writes part.

    hipLaunchKernelGGL(prep_kernel, dim3(TSTEPS + 144), dim3(256), 0, stream,
                       cm, cmP, x, ps);
    hipLaunchKernelGGL(reduce_s_kernel, dim3(NN), dim3(256), 0, stream, ps, sbuf);
    hipLaunchKernelGGL(gemm_kernel, dim3(16 * SPLITK), dim3(256), 0, stream,
                       x, sbuf, cmP, part);
    hipLaunchKernelGGL(reduce_ln_kernel, dim3(NN), dim3(256), 0, stream,
                       x, part, gamma, beta, out);
}

// Round 15
// 75.187 us; speedup vs baseline: 1.9646x; 1.0893x over previous
//
#include <hip/hip_runtime.h>
#include <hip/hip_fp16.h>
#include <cstdint>

#define BB 2
#define SS 512
#define EE 256
#define NN (BB*SS)           // 1024 rows
#define KTOT (EE*EE)         // 65536
#define SPLITK 32
#define KCHUNK (KTOT/SPLITK) // 2048
#define NSTEP (KCHUNK/32)    // 64 k-steps per chunk
#define TSTEPS (KTOT/32)     // 2048 total k-steps
#define LN_EPS 1e-3f

typedef _Float16 f16;
typedef _Float16 f16x8 __attribute__((ext_vector_type(8)));
typedef float    f32x4 __attribute__((ext_vector_type(4)));

#define NPACK 512            // pack blocks: 4 cgroups x 128 kgroups

// ---------------- Kernel 1: FUSED pack (LDS transpose) + wprefix.
// Blocks [0, NPACK): pack cm f32 -> cmP f16, coalesced both sides.
//   Block (cg = bid>>7, kg = bid&127): rows [cg*64,+64), k [kg*512,+512).
//   Two 32-row halves; per half:
//     A: coalesced read (lane-contig k), cvt f16, LDS scatter [slot=lane][row]
//     B: linear LDS read, coalesced cmP write (512B runs).
// Blocks [NPACK, NPACK+144): triangular weighted prefix partials.
__global__ void prep_kernel(const float* __restrict__ cm, f16* __restrict__ cmP,
                            const float* __restrict__ x, float* __restrict__ ps) {
    __shared__ __align__(16) char smem[35072];
    const int bid = blockIdx.x;
    const int tid = threadIdx.x;
    const int wave = tid >> 6;
    const int lane = tid & 63;

    if (bid < NPACK) {
        const int cg = bid >> 7;          // 0..3
        const int kg = bid & 127;         // 0..127
        f16* lt = (f16*)smem;             // [64 slots][264] (pad 8)
        #pragma unroll
        for (int h = 0; h < 2; ++h) {
            // ---- phase A: load 32 rows x 512 k, coalesced
            #pragma unroll
            for (int i = 0; i < 8; ++i) {
                const int rl = i * 4 + wave;                   // 0..31
                const int row = cg * 64 + h * 32 + rl;
                const float* src = cm + (size_t)row * KTOT + kg * 512 + lane * 8;
                float4 lo = *(const float4*)(src);
                float4 hi = *(const float4*)(src + 4);
                f16x8 v = { (f16)lo.x, (f16)lo.y, (f16)lo.z, (f16)lo.w,
                            (f16)hi.x, (f16)hi.y, (f16)hi.z, (f16)hi.w };
                // slot = lane (t_l = lane>>2, koct = lane&3), col = rl
                *(f16x8*)(lt + lane * 264 + rl * 8) = v;
            }
            __syncthreads();
            // ---- phase B: linear LDS read, coalesced cmP store
            #pragma unroll
            for (int jj = 0; jj < 8; ++jj) {
                const int s  = jj * 8 + wave * 2 + (lane >> 5);  // slot 0..63
                const int cl = lane & 31;
                f16x8 v = *(const f16x8*)(lt + s * 264 + cl * 8);
                const int t    = kg * 16 + (s >> 2);
                const int koct = s & 3;
                const int c    = cg * 64 + h * 32 + cl;
                *(f16x8*)(cmP + (size_t)t * 8192 + koct * 2048 + c * 8) = v;
            }
            __syncthreads();
        }
        return;
    }

    // ---- wprefix
    float (*xt)[128] = (float(*)[128])smem;            // 64 x 128 f32
    float* wl2 = (float*)(smem + 32768);               // 576 f32
    const int id = bid - NPACK;            // 0..143
    const int eh = id & 1;
    const int rest = id >> 1;
    const int b = rest / 36;
    const int r = rest % 36;
    int it = 0;
    while ((it + 1) * (it + 2) / 2 <= r) ++it;
    const int jt = r - it * (it + 1) / 2;

    for (int t = tid; t < 576; t += 256) {
        const int d = t - 64;
        wl2[t] = (d > 0) ? 1.0f / ((float)d * (float)d) : 0.0f;
    }
    const int jbase = jt * 64, ibase = it * 64;
    const float* xb = x + ((size_t)b * SS + jbase) * EE + eh * 128;
    #pragma unroll
    for (int p = 0; p < 8; ++p) {
        const int row = p * 8 + (tid >> 5);
        const int col = (tid & 31) * 4;
        *(float4*)&xt[row][col] = *(const float4*)(xb + (size_t)row * EE + col);
    }
    __syncthreads();

    const int g  = tid >> 5;
    const int ec = (tid & 31) * 4;
    const int irow = ibase + g * 8;
    float4 acc[8];
    #pragma unroll
    for (int m = 0; m < 8; ++m) acc[m] = (float4){0.f, 0.f, 0.f, 0.f};

    for (int jj = 0; jj < 64; ++jj) {
        const float4 xv = *(const float4*)&xt[jj][ec];
        const int wbase = irow - (jbase + jj) + 64;
        #pragma unroll
        for (int m = 0; m < 8; ++m) {
            const float w = wl2[wbase + m];
            acc[m].x += xv.x * w;
            acc[m].y += xv.y * w;
            acc[m].z += xv.z * w;
            acc[m].w += xv.w * w;
        }
    }

    float* base = ps + ((size_t)(((b * 2 + eh) * 8 + it) * 8 + jt)) * (64 * 128);
    #pragma unroll
    for (int m = 0; m < 8; ++m)
        *(float4*)(base + (size_t)(g * 8 + m) * 128 + ec) = acc[m];
}

// ---------------- Kernel 1b: fold j-tile partials -> s[n,e]
__global__ void reduce_s_kernel(const float* __restrict__ ps, float* __restrict__ s) {
    const int n = blockIdx.x;
    const int e = threadIdx.x;
    const int b = n >> 9, i = n & (SS - 1);
    const int it = i >> 6, il = i & 63;
    const int eh = e >> 7, ec = e & 127;
    const size_t tbase = (size_t)((b * 2 + eh) * 8 + it) * 8;
    float acc = 0.0f;
    for (int jt = 0; jt <= it; ++jt)
        acc += ps[(tbase + jt) * (64 * 128) + (size_t)il * 128 + ec];
    s[(size_t)n * EE + e] = acc;
}

// ---------------- Kernel 2: split-K MFMA GEMM — R14 main loop (barrier-free,
// depth-3, tail bf/af prefetch, pk-mul af) + f16 LDS-staged epilogue.
__launch_bounds__(256, 2)
__global__ void gemm_kernel(const float* __restrict__ x,
                            const float* __restrict__ sbuf,
                            const f16* __restrict__ cmP,
                            f16* __restrict__ part) {
    __shared__ __align__(16) f16 Bs[4][8192];   // 4 x 16 KB
    const int tid  = threadIdx.x;
    const int lane = tid & 63;
    const int wave = tid >> 6;       // col-quarter 0..3
    const int koct = lane >> 4;      // k-octet 0..3
    const int cl   = lane & 15;

    const int d = blockIdx.x;            // 0..511
    const int nblock = (d >> 3) & 15;
    const int chunk  = (d & 7) * 4 + (d >> 7);   // XCD-grouped chunks

    // ---- xf loads (8 global loads)
    f16x8 xf[4];
    #pragma unroll
    for (int rt = 0; rt < 4; ++rt) {
        const int r = nblock * 64 + rt * 16 + cl;
        const float* xr = x + (size_t)r * EE + chunk * 8;
        float4 xlo = *(const float4*)(xr);
        float4 xhi = *(const float4*)(xr + 4);
        xf[rt] = (f16x8){ (f16)xlo.x, (f16)xlo.y, (f16)xlo.z, (f16)xlo.w,
                          (f16)xhi.x, (f16)xhi.y, (f16)xhi.z, (f16)xhi.w };
    }
    // ---- svm m=0 loads (8 global loads)
    float4 p0[4][2];
    #pragma unroll
    for (int rt = 0; rt < 4; ++rt) {
        const int r = nblock * 64 + rt * 16 + cl;
        const float* sr = sbuf + (size_t)r * EE + koct * 8;
        p0[rt][0] = *(const float4*)(sr);
        p0[rt][1] = *(const float4*)(sr + 4);
    }
    __builtin_amdgcn_sched_barrier(0);   // pin: xf/svm issued before stages

    f32x4 acc[4][4];
    #pragma unroll
    for (int a = 0; a < 4; ++a)
        #pragma unroll
        for (int b = 0; b < 4; ++b) acc[a][b] = (f32x4){0.f, 0.f, 0.f, 0.f};

    const char* srcBase = (const char*)cmP + (size_t)(chunk * NSTEP) * 16384;
    auto stageV = [&](int v) {
        const int t = ((v & 7) << 3) | (v >> 3);
        const char* g = srcBase + (size_t)t * 16384 + wave * 1024 + lane * 16;
        char* l = (char*)&Bs[v & 3][0] + wave * 1024;
        #pragma unroll
        for (int i = 0; i < 4; ++i) {
            __builtin_amdgcn_global_load_lds(
                (const __attribute__((address_space(1))) void*)(g + i * 4096),
                (__attribute__((address_space(3))) void*)(l + i * 4096),
                16, 0, 0);
        }
    };

    stageV(0); stageV(1); stageV(2);     // 12 loads in flight (per wave)
    asm volatile("s_waitcnt vmcnt(8)" ::: "memory");   // xf, svm, stage(0) done
    __builtin_amdgcn_sched_barrier(0);

    f16x8 svm[4];
    #pragma unroll
    for (int rt = 0; rt < 4; ++rt)
        svm[rt] = (f16x8){ (f16)p0[rt][0].x, (f16)p0[rt][0].y,
                           (f16)p0[rt][0].z, (f16)p0[rt][0].w,
                           (f16)p0[rt][1].x, (f16)p0[rt][1].y,
                           (f16)p0[rt][1].z, (f16)p0[rt][1].w };

    const int cb = koct * 2048 + (wave * 64 + cl) * 8;

    // bf(0) read + af(0) build
    f16x8 bfc[4], afc[4];
    {
        const f16* bb = &Bs[0][cb];
        #pragma unroll
        for (int ct = 0; ct < 4; ++ct) bfc[ct] = *(const f16x8*)(bb + ct * 128);
        #pragma unroll
        for (int rt = 0; rt < 4; ++rt) {
            const f16 xa = xf[rt][0];
            const f16x8 xa8 = { xa, xa, xa, xa, xa, xa, xa, xa };
            afc[rt] = xa8 * svm[rt];
        }
    }

    #pragma unroll
    for (int m = 0; m < 8; ++m) {
        float4 pnxt[4][2];
        #pragma unroll
        for (int a_l = 0; a_l < 8; ++a_l) {
            const int v = m * 8 + a_l;

            if (a_l == 6 && m < 7) {
                #pragma unroll
                for (int rt = 0; rt < 4; ++rt) {
                    const int r = nblock * 64 + rt * 16 + cl;
                    const float* sr = sbuf + (size_t)r * EE + (m + 1) * 32 + koct * 8;
                    pnxt[rt][0] = *(const float4*)(sr);
                    pnxt[rt][1] = *(const float4*)(sr + 4);
                }
                __builtin_amdgcn_sched_barrier(0);
            }

            // MFMA cluster (16) — operands prefetched last step
            __builtin_amdgcn_s_setprio(1);
            #pragma unroll
            for (int ct = 0; ct < 4; ++ct)
                #pragma unroll
                for (int rt = 0; rt < 4; ++rt)
                    acc[rt][ct] = __builtin_amdgcn_mfma_f32_16x16x32_f16(afc[rt], bfc[ct], acc[rt][ct], 0, 0, 0);
            __builtin_amdgcn_s_setprio(0);

            if (v + 3 < NSTEP) stageV(v + 3);

            if (v <= 60) {
                if (a_l == 6 && m < 7) asm volatile("s_waitcnt vmcnt(16)" ::: "memory");
                else                   asm volatile("s_waitcnt vmcnt(8)"  ::: "memory");
            } else if (v == 61)        asm volatile("s_waitcnt vmcnt(4)"  ::: "memory");
            else if (v == 62)          asm volatile("s_waitcnt vmcnt(0)"  ::: "memory");
            __builtin_amdgcn_sched_barrier(0);

            // tail prefetch: bf(v+1) + af(v+1)
            if (v < 63) {
                const f16* bb = &Bs[0][0] + (size_t)((v + 1) & 3) * 8192 + cb;
                f16x8 bfn[4];
                #pragma unroll
                for (int ct = 0; ct < 4; ++ct) bfn[ct] = *(const f16x8*)(bb + ct * 128);
                if (a_l == 7) {
                    #pragma unroll
                    for (int rt = 0; rt < 4; ++rt)
                        svm[rt] = (f16x8){ (f16)pnxt[rt][0].x, (f16)pnxt[rt][0].y,
                                           (f16)pnxt[rt][0].z, (f16)pnxt[rt][0].w,
                                           (f16)pnxt[rt][1].x, (f16)pnxt[rt][1].y,
                                           (f16)pnxt[rt][1].z, (f16)pnxt[rt][1].w };
                }
                #pragma unroll
                for (int rt = 0; rt < 4; ++rt) {
                    const f16 xa = xf[rt][(a_l + 1) & 7];
                    const f16x8 xa8 = { xa, xa, xa, xa, xa, xa, xa, xa };
                    afc[rt] = xa8 * svm[rt];
                }
                #pragma unroll
                for (int ct = 0; ct < 4; ++ct) bfc[ct] = bfn[ct];
                __builtin_amdgcn_sched_barrier(0);
            }
        }
    }

    // ---- Epilogue: f16 via padded LDS stage, then contiguous row stores.
    __syncthreads();                      // rendezvous drifted waves; Bs free
    f16* Ep = (f16*)&Bs[0][0];            // [64][264] padded, 33.8 KB
    #pragma unroll
    for (int rt = 0; rt < 4; ++rt) {
        #pragma unroll
        for (int ct = 0; ct < 4; ++ct) {
            const int col = wave * 64 + ct * 16 + cl;
            #pragma unroll
            for (int q = 0; q < 4; ++q) {
                const int lr = rt * 16 + koct * 4 + q;
                Ep[lr * 264 + col] = (f16)acc[rt][ct][q];
            }
        }
    }
    __syncthreads();
    {
        const int lr  = tid >> 2;         // 0..63
        const int seg = tid & 3;          // 0..3 (64 cols each)
        f16* dst = part + ((size_t)chunk * NN + nblock * 64 + lr) * EE + seg * 64;
        const f16* srcE = Ep + lr * 264 + seg * 64;
        #pragma unroll
        for (int i = 0; i < 8; ++i)
            *(f16x8*)(dst + i * 8) = *(const f16x8*)(srcE + i * 8);
    }
}

// ---------------- Kernel 3: split-K reduce + residual + LayerNorm (f16 partials)
__global__ void reduce_ln_kernel(const float* __restrict__ x,
                                 const f16* __restrict__ part,
                                 const float* __restrict__ gamma,
                                 const float* __restrict__ beta,
                                 float* __restrict__ out) {
    const int n = blockIdx.x;
    const int c = threadIdx.x;
    const int lane = c & 63, wave = c >> 6;
    float y = x[(size_t)n * EE + c];
    #pragma unroll 8
    for (int ch = 0; ch < SPLITK; ++ch)
        y += (float)part[((size_t)ch * NN + n) * EE + c];

    float v = y;
    #pragma unroll
    for (int o = 32; o > 0; o >>= 1) v += __shfl_xor(v, o);
    __shared__ float red[8];
    if (lane == 0) red[wave] = v;
    __syncthreads();
    const float mean = (red[0] + red[1] + red[2] + red[3]) * (1.0f / EE);
    const float d = y - mean;
    float sq = d * d;
    #pragma unroll
    for (int o = 32; o > 0; o >>= 1) sq += __shfl_xor(sq, o);
    if (lane == 0) red[4 + wave] = sq;
    __syncthreads();
    const float var = (red[4] + red[5] + red[6] + red[7]) * (1.0f / EE);
    out[(size_t)n * EE + c] = d * rsqrtf(var + LN_EPS) * gamma[c] + beta[c];
}

extern "C" void kernel_launch(void* const* d_in, const int* in_sizes, int n_in,
                              void* d_out, int out_size, void* d_ws, size_t ws_size,
                              hipStream_t stream) {
    const float* x     = (const float*)d_in[0];
    const float* cm    = (const float*)d_in[1];
    const float* gamma = (const float*)d_in[2];
    const float* beta  = (const float*)d_in[3];
    float* out = (float*)d_out;

    float* sbuf = (float*)d_ws;                                    // 1 MB
    f16*   cmP  = (f16*)(sbuf + (size_t)NN * EE);                  // 33.5 MB
    f16*   part = (f16*)((char*)cmP + (size_t)TSTEPS * 8192 * sizeof(f16)); // 16.8 MB
    float* ps   = (float*)part;  // prefix partials (8.4 MB) alias part —
                                 // consumed by reduce_s before gemm writes part.

    hipLaunchKernelGGL(prep_kernel, dim3(NPACK + 144), dim3(256), 0, stream,
                       cm, cmP, x, ps);
    hipLaunchKernelGGL(reduce_s_kernel, dim3(NN), dim3(256), 0, stream, ps, sbuf);
    hipLaunchKernelGGL(gemm_kernel, dim3(16 * SPLITK), dim3(256), 0, stream,
                       x, sbuf, cmP, part);
    hipLaunchKernelGGL(reduce_ln_kernel, dim3(NN), dim3(256), 0, stream,
                       x, part, gamma, beta, out);
}